// Round 5
// 478.533 us; speedup vs baseline: 1.1461x; 1.1461x over previous
//
#include <hip/hip_runtime.h>

#define E_TOT   300000
#define D_DIM   256
#define N_EXP   5
#define BM      64
#define LDK     264           // bf16 A-tile stride: 256 + 8 pad (2-way bank alias = free)
#define LDF     260           // f32 epilogue scratch stride (2-way alias = free)
#define NB_CNT  ((E_TOT + 255) / 256)          // 1172
#define MAX_TILES (E_TOT / BM + N_EXP)         // 4697

typedef __attribute__((ext_vector_type(8))) short bf16x8;
typedef __attribute__((ext_vector_type(4))) float f32x4;

__device__ inline unsigned short f2bf(float f) {
  union { float f; unsigned u; } v; v.f = f;
  unsigned u = v.u;
  u += 0x7FFFu + ((u >> 16) & 1u);   // round-to-nearest-even
  return (unsigned short)(u >> 16);
}

__device__ inline int get_expert(const void* masks, int e, bool is_u8) {
  if (is_u8) {
    const unsigned char* m = (const unsigned char*)masks;
#pragma unroll
    for (int i = 0; i < N_EXP; ++i) if (m[(size_t)i * E_TOT + e]) return i;
  } else {
    const int* m = (const int*)masks;
#pragma unroll
    for (int i = 0; i < N_EXP; ++i) if (m[(size_t)i * E_TOT + e]) return i;
  }
  return 0;
}

// ---- node 2: layout self-detect + per-expert counts + W f32->bf16 ----
// u8-probe: masks are one-hot per slot, so u8 layout <=> every slot sees exactly one
// true byte. On i32 data read as u8, slots with e%4!=0 hit i32 high bytes (all 0) ->
// cnt==0 -> every block (256 consecutive slots) detects i32. Deterministic, grid-consistent.
__global__ void prep_kernel(const float* __restrict__ W, unsigned short* __restrict__ Wbf,
                            const void* __restrict__ masks, int* __restrict__ hdr,
                            int doConv) {
  __shared__ int wc[4][N_EXP];
  __shared__ int s_u8ok;
  const int tt = threadIdx.x, w = tt >> 6, lane = tt & 63;
  const int gtid = (int)blockIdx.x * 256 + tt;

  const unsigned char* m8 = (const unsigned char*)masks;
  int cnt1 = 1, ex = -1;
  if (gtid < E_TOT) {
    cnt1 = 0; int exu = 0;
#pragma unroll
    for (int i = 0; i < N_EXP; ++i) {
      int tb = (m8[(size_t)i * E_TOT + gtid] != 0);
      cnt1 += tb; if (tb) exu = i;
    }
    ex = exu;
  }
  if (tt == 0) s_u8ok = 1;
  __syncthreads();
  if (cnt1 != 1) s_u8ok = 0;         // benign all-write-0 race
  __syncthreads();
  const int is_u8 = s_u8ok;
  if (!is_u8 && gtid < E_TOT) ex = get_expert(masks, gtid, false);

#pragma unroll
  for (int i = 0; i < N_EXP; ++i) {
    unsigned long long bal = __ballot(ex == i);
    if (lane == 0) wc[w][i] = __popcll(bal);
  }
  if (doConv) {
    const int n4 = (N_EXP * D_DIM * D_DIM) / 4;   // 81920 float4s
    for (int i = gtid; i < n4; i += (int)gridDim.x * 256) {
      float4 v = ((const float4*)W)[i];
      ushort4 o4;
      o4.x = f2bf(v.x); o4.y = f2bf(v.y); o4.z = f2bf(v.z); o4.w = f2bf(v.w);
      ((ushort4*)Wbf)[i] = o4;
    }
  }
  __syncthreads();
  if (tt < N_EXP)
    atomicAdd(&hdr[tt], wc[0][tt] + wc[1][tt] + wc[2][tt] + wc[3][tt]);
  if (tt == 0 && blockIdx.x == 0) hdr[6] = is_u8;   // publish verdict for scatter
}

// ---- node 3: scatter via per-block atomic cursors (order within bucket irrelevant) ----
__global__ void scatter_kernel(const void* __restrict__ masks, const int* __restrict__ hdr,
                               int* __restrict__ cursor, int* __restrict__ perm) {
  __shared__ int wc[4][N_EXP];
  __shared__ int wo[4][N_EXP];
  __shared__ int bb[N_EXP];
  const int tt = threadIdx.x, w = tt >> 6, lane = tt & 63;
  const int e = (int)blockIdx.x * 256 + tt;
  const bool is_u8 = (hdr[6] != 0);   // finalized by prep dispatch

  int ex = (e < E_TOT) ? get_expert(masks, e, is_u8) : -1;
  unsigned long long myBal = 0;
#pragma unroll
  for (int i = 0; i < N_EXP; ++i) {
    unsigned long long bal = __ballot(ex == i);
    if (lane == 0) wc[w][i] = __popcll(bal);
    if (ex == i) myBal = bal;
  }
  __syncthreads();
  if (tt < 4 * N_EXP) {
    int ww = tt / N_EXP, ii = tt % N_EXP;
    int s = 0;
    for (int p = 0; p < ww; ++p) s += wc[p][ii];
    wo[ww][ii] = s;
  }
  if (tt < N_EXP) {
    int tot = wc[0][tt] + wc[1][tt] + wc[2][tt] + wc[3][tt];
    int old = atomicAdd(&cursor[tt], tot);
    int base = 0;
    for (int i = 0; i < tt; ++i) base += hdr[i];   // counts final after prep dispatch
    bb[tt] = base + old;
  }
  __syncthreads();
  if (ex >= 0) {
    int rank = __popcll(myBal & ((1ull << lane) - 1ull));
    perm[bb[ex] + wo[w][ex] + rank] = e;
  }
}

// ---- node 4: GEMM, BM=64, A in LDS (4 blocks/CU), LDS-transpose epilogue ----
template <bool PRE>
__launch_bounds__(256, 4)
__global__ void gemm_kernel(const float* __restrict__ x, const float* __restrict__ W,
                            const unsigned short* __restrict__ Wbf,
                            const float* __restrict__ bias, const int* __restrict__ index,
                            const int* __restrict__ hdr, const int* __restrict__ perm,
                            float* __restrict__ out) {
  __shared__ __align__(16) unsigned short lA[BM * LDK];   // 33.75 KB, reused as f32 scratch
  __shared__ int srcRow[BM];
  __shared__ int outRow[BM];

  // block -> (expert, row-tile); bucket bases via local prefix over hdr counts
  int t = (int)blockIdx.x;
  int ex = -1, trow = 0, cnt = 0, accT = 0, base = 0, run = 0;
#pragma unroll
  for (int i = 0; i < N_EXP; ++i) {
    int c = hdr[i];
    int nt = (c + BM - 1) / BM;
    if (ex < 0 && t < accT + nt) { ex = i; trow = t - accT; cnt = c; base = run; }
    accT += nt;
    run += c;
  }
  if (ex < 0) return;
  int row0 = base + trow * BM;
  int rows = min(BM, cnt - trow * BM);

  const int tt = threadIdx.x;
  if (tt < BM) {
    int rr = min(tt, rows - 1);       // tail: duplicate last valid row, masked at store
    int e = perm[row0 + rr];
    outRow[tt] = e;
    srcRow[tt] = index[e];
  }
  __syncthreads();

  // stage A: gather 64 rows x 256 f32 -> bf16 LDS (1KB coalesced per row)
#pragma unroll
  for (int i = 0; i < 16; ++i) {
    int lin = i * 256 + tt;
    int rr = lin >> 6;
    int c4 = lin & 63;
    const float4 v = ((const float4*)(x + (size_t)srcRow[rr] * D_DIM))[c4];
    ushort4 o4;
    o4.x = f2bf(v.x); o4.y = f2bf(v.y); o4.z = f2bf(v.z); o4.w = f2bf(v.w);
    *(ushort4*)&lA[rr * LDK + c4 * 4] = o4;
  }
  __syncthreads();

  const int w = tt >> 6, lane = tt & 63, quad = lane >> 4, l16 = lane & 15;

  // K-loop: wave w owns cols [w*64, w*64+64)
  f32x4 acc[4][4];
#pragma unroll
  for (int mt = 0; mt < 4; ++mt)
#pragma unroll
    for (int nt = 0; nt < 4; ++nt) acc[mt][nt] = (f32x4){0.f, 0.f, 0.f, 0.f};

#pragma unroll
  for (int ks = 0; ks < 8; ++ks) {
    int k0 = ks * 32 + quad * 8;
    bf16x8 a[4], b[4];
#pragma unroll
    for (int mt = 0; mt < 4; ++mt)
      a[mt] = *(const bf16x8*)&lA[(mt * 16 + l16) * LDK + k0];
#pragma unroll
    for (int nt = 0; nt < 4; ++nt) {
      int col = w * 64 + nt * 16 + l16;   // W row (output col)
      if (PRE) {
        b[nt] = *(const bf16x8*)&Wbf[((size_t)ex * D_DIM + col) * D_DIM + k0];
      } else {
        const float* wp = W + ((size_t)ex * D_DIM + col) * D_DIM + k0;
        float4 v0 = ((const float4*)wp)[0];
        float4 v1 = ((const float4*)wp)[1];
        bf16x8 bb;
        bb[0] = (short)f2bf(v0.x); bb[1] = (short)f2bf(v0.y);
        bb[2] = (short)f2bf(v0.z); bb[3] = (short)f2bf(v0.w);
        bb[4] = (short)f2bf(v1.x); bb[5] = (short)f2bf(v1.y);
        bb[6] = (short)f2bf(v1.z); bb[7] = (short)f2bf(v1.w);
        b[nt] = bb;
      }
    }
#pragma unroll
    for (int mt = 0; mt < 4; ++mt)
#pragma unroll
      for (int nt = 0; nt < 4; ++nt)
        acc[mt][nt] = __builtin_amdgcn_mfma_f32_16x16x32_bf16(a[mt], b[nt], acc[mt][nt], 0, 0, 0);
  }

  // bias (reused across both chunks)
  float bv[4];
#pragma unroll
  for (int nt = 0; nt < 4; ++nt) bv[nt] = bias[ex * D_DIM + w * 64 + nt * 16 + l16];

  // epilogue: transpose 32-row chunks through LDS -> contiguous 128B nontemporal row stores
  float* lsf = (float*)lA;   // 32 x LDF f32 scratch (33280B <= 33792B)
#pragma unroll
  for (int chunk = 0; chunk < 2; ++chunk) {
    __syncthreads();   // lA/lsf reads (K-loop / prev chunk) complete before overwrite
#pragma unroll
    for (int mtl = 0; mtl < 2; ++mtl) {
      int mt = chunk * 2 + mtl;
#pragma unroll
      for (int nt = 0; nt < 4; ++nt) {
        int col = w * 64 + nt * 16 + l16;
#pragma unroll
        for (int r = 0; r < 4; ++r) {
          int lr = mtl * 16 + quad * 4 + r;           // chunk-local row 0..31
          lsf[lr * LDF + col] = acc[mt][nt][r] + bv[nt];
        }
      }
    }
    __syncthreads();
    int r8 = tt >> 3, c8 = tt & 7;
    int grow = chunk * 32 + r8;
    if (grow < rows) {
      float* op = out + (size_t)outRow[grow] * D_DIM;
#pragma unroll
      for (int j = 0; j < 8; ++j) {
        int c4 = c8 + j * 8;                           // 8 lanes -> 128B contiguous per row
        f32x4 v4 = *(const f32x4*)&lsf[r8 * LDF + c4 * 4];
        __builtin_nontemporal_store(v4, (f32x4*)(op + c4 * 4));
      }
    }
  }
}

extern "C" void kernel_launch(void* const* d_in, const int* in_sizes, int n_in,
                              void* d_out, int out_size, void* d_ws, size_t ws_size,
                              hipStream_t stream) {
  const float* x     = (const float*)d_in[0];
  const float* W     = (const float*)d_in[1];
  const float* bias  = (const float*)d_in[2];
  const int*   index = (const int*)d_in[3];
  const void*  masks = d_in[4];
  float* out = (float*)d_out;

  int* hdr = (int*)d_ws;               // [0..4] counts, [6] is_u8, [16..20] cursors
  const size_t wbfB  = (size_t)N_EXP * D_DIM * D_DIM * 2;  // 655360
  const size_t permB = (size_t)E_TOT * 4;                  // 1.2 MB
  bool pre = (ws_size >= 1024 + wbfB + permB);
  size_t off = 1024;
  unsigned short* Wbf = nullptr;
  if (pre) { Wbf = (unsigned short*)((char*)d_ws + off); off += wbfB; }
  int* perm = (int*)((char*)d_ws + off);

  (void)hipMemsetAsync(d_ws, 0, 1024, stream);   // zero counts + cursors each replay
  prep_kernel<<<NB_CNT, 256, 0, stream>>>(W, Wbf, masks, hdr, pre ? 1 : 0);
  scatter_kernel<<<NB_CNT, 256, 0, stream>>>(masks, hdr, hdr + 16, perm);
  if (pre)
    gemm_kernel<true><<<MAX_TILES, 256, 0, stream>>>(x, W, Wbf, bias, index, hdr, perm, out);
  else
    gemm_kernel<false><<<MAX_TILES, 256, 0, stream>>>(x, W, Wbf, bias, index, hdr, perm, out);
}

// Round 6
// 463.361 us; speedup vs baseline: 1.1836x; 1.0327x over previous
//
#include <hip/hip_runtime.h>

#define E_TOT   300000
#define D_DIM   256
#define N_EXP   5
#define BM      64
#define LDK     264           // bf16 A-tile stride: 256 + 8 pad (2-way bank alias = free)
#define LDF     260           // f32 epilogue scratch stride (2-way alias = free)
#define NB_CNT  ((E_TOT + 255) / 256)          // 1172
#define MAX_TILES (E_TOT / BM + N_EXP)         // 4697

typedef __attribute__((ext_vector_type(8))) short bf16x8;
typedef __attribute__((ext_vector_type(4))) float f32x4;

__device__ inline unsigned short f2bf(float f) {
  union { float f; unsigned u; } v; v.f = f;
  unsigned u = v.u;
  u += 0x7FFFu + ((u >> 16) & 1u);   // round-to-nearest-even
  return (unsigned short)(u >> 16);
}

__device__ inline int get_expert(const void* masks, int e, bool is_u8) {
  if (is_u8) {
    const unsigned char* m = (const unsigned char*)masks;
#pragma unroll
    for (int i = 0; i < N_EXP; ++i) if (m[(size_t)i * E_TOT + e]) return i;
  } else {
    const int* m = (const int*)masks;
#pragma unroll
    for (int i = 0; i < N_EXP; ++i) if (m[(size_t)i * E_TOT + e]) return i;
  }
  return 0;
}

// ======== 3-node path: single-pass scatter into FIXED expert regions (ex*E_TOT) ========
// No count pass needed: bucket bases are fixed, blocks reserve ranges via 5 atomic
// cursors; gemm reads finalized cursors as counts. Masks read exactly once.
// u8-vs-i32 self-detect per block: masks are one-hot per slot, so u8 layout <=> every
// slot has exactly one true byte; i32 misread as u8 gives cnt==0 for e%4!=0 slots,
// which every 256-slot block contains. Deterministic and grid-consistent.
__global__ void scatter_conv_kernel(const float* __restrict__ W,
                                    unsigned short* __restrict__ Wbf,
                                    const void* __restrict__ masks,
                                    int* __restrict__ cursor, int* __restrict__ perm,
                                    int doConv) {
  __shared__ int wc[4][N_EXP];
  __shared__ int wo[4][N_EXP];
  __shared__ int bb[N_EXP];
  __shared__ int s_u8ok;
  const int tt = threadIdx.x, w = tt >> 6, lane = tt & 63;
  const int e = (int)blockIdx.x * 256 + tt;

  const unsigned char* m8 = (const unsigned char*)masks;
  int cnt1 = 1, ex = -1;
  if (e < E_TOT) {
    cnt1 = 0; int exu = 0;
#pragma unroll
    for (int i = 0; i < N_EXP; ++i) {
      int tb = (m8[(size_t)i * E_TOT + e] != 0);
      cnt1 += tb; if (tb) exu = i;
    }
    ex = exu;
  }
  if (tt == 0) s_u8ok = 1;
  __syncthreads();
  if (cnt1 != 1) s_u8ok = 0;         // benign all-write-0 race
  __syncthreads();
  if (!s_u8ok && e < E_TOT) ex = get_expert(masks, e, false);

  unsigned long long myBal = 0;
#pragma unroll
  for (int i = 0; i < N_EXP; ++i) {
    unsigned long long bal = __ballot(ex == i);
    if (lane == 0) wc[w][i] = __popcll(bal);
    if (ex == i) myBal = bal;
  }
  // W f32->bf16 convert overlaps the ballot/scan sync (first 320 blocks only)
  if (doConv) {
    const int n4 = (N_EXP * D_DIM * D_DIM) / 4;   // 81920 float4s
    for (int i = e; i < n4; i += (int)gridDim.x * 256) {
      float4 v = ((const float4*)W)[i];
      ushort4 o4;
      o4.x = f2bf(v.x); o4.y = f2bf(v.y); o4.z = f2bf(v.z); o4.w = f2bf(v.w);
      ((ushort4*)Wbf)[i] = o4;
    }
  }
  __syncthreads();
  if (tt < 4 * N_EXP) {
    int ww = tt / N_EXP, ii = tt % N_EXP;
    int s = 0;
    for (int p = 0; p < ww; ++p) s += wc[p][ii];
    wo[ww][ii] = s;
  }
  if (tt < N_EXP) {
    int tot = wc[0][tt] + wc[1][tt] + wc[2][tt] + wc[3][tt];
    int old = atomicAdd(&cursor[tt], tot);
    bb[tt] = tt * E_TOT + old;        // fixed expert region base
  }
  __syncthreads();
  if (ex >= 0) {
    int rank = __popcll(myBal & ((1ull << lane) - 1ull));
    perm[bb[ex] + wo[w][ex] + rank] = e;
  }
}

// ======== fallback (small ws): R5's 4-node prep+scatter, compact perm ========
__global__ void prep_kernel(const float* __restrict__ W, unsigned short* __restrict__ Wbf,
                            const void* __restrict__ masks, int* __restrict__ hdr,
                            int doConv) {
  __shared__ int wc[4][N_EXP];
  __shared__ int s_u8ok;
  const int tt = threadIdx.x, w = tt >> 6, lane = tt & 63;
  const int gtid = (int)blockIdx.x * 256 + tt;

  const unsigned char* m8 = (const unsigned char*)masks;
  int cnt1 = 1, ex = -1;
  if (gtid < E_TOT) {
    cnt1 = 0; int exu = 0;
#pragma unroll
    for (int i = 0; i < N_EXP; ++i) {
      int tb = (m8[(size_t)i * E_TOT + gtid] != 0);
      cnt1 += tb; if (tb) exu = i;
    }
    ex = exu;
  }
  if (tt == 0) s_u8ok = 1;
  __syncthreads();
  if (cnt1 != 1) s_u8ok = 0;
  __syncthreads();
  const int is_u8 = s_u8ok;
  if (!is_u8 && gtid < E_TOT) ex = get_expert(masks, gtid, false);

#pragma unroll
  for (int i = 0; i < N_EXP; ++i) {
    unsigned long long bal = __ballot(ex == i);
    if (lane == 0) wc[w][i] = __popcll(bal);
  }
  if (doConv) {
    const int n4 = (N_EXP * D_DIM * D_DIM) / 4;
    for (int i = gtid; i < n4; i += (int)gridDim.x * 256) {
      float4 v = ((const float4*)W)[i];
      ushort4 o4;
      o4.x = f2bf(v.x); o4.y = f2bf(v.y); o4.z = f2bf(v.z); o4.w = f2bf(v.w);
      ((ushort4*)Wbf)[i] = o4;
    }
  }
  __syncthreads();
  if (tt < N_EXP)
    atomicAdd(&hdr[tt], wc[0][tt] + wc[1][tt] + wc[2][tt] + wc[3][tt]);
  if (tt == 0 && blockIdx.x == 0) hdr[6] = is_u8;
}

__global__ void scatter_kernel(const void* __restrict__ masks, const int* __restrict__ hdr,
                               int* __restrict__ cursor, int* __restrict__ perm) {
  __shared__ int wc[4][N_EXP];
  __shared__ int wo[4][N_EXP];
  __shared__ int bb[N_EXP];
  const int tt = threadIdx.x, w = tt >> 6, lane = tt & 63;
  const int e = (int)blockIdx.x * 256 + tt;
  const bool is_u8 = (hdr[6] != 0);

  int ex = (e < E_TOT) ? get_expert(masks, e, is_u8) : -1;
  unsigned long long myBal = 0;
#pragma unroll
  for (int i = 0; i < N_EXP; ++i) {
    unsigned long long bal = __ballot(ex == i);
    if (lane == 0) wc[w][i] = __popcll(bal);
    if (ex == i) myBal = bal;
  }
  __syncthreads();
  if (tt < 4 * N_EXP) {
    int ww = tt / N_EXP, ii = tt % N_EXP;
    int s = 0;
    for (int p = 0; p < ww; ++p) s += wc[p][ii];
    wo[ww][ii] = s;
  }
  if (tt < N_EXP) {
    int tot = wc[0][tt] + wc[1][tt] + wc[2][tt] + wc[3][tt];
    int old = atomicAdd(&cursor[tt], tot);
    int base = 0;
    for (int i = 0; i < tt; ++i) base += hdr[i];
    bb[tt] = base + old;
  }
  __syncthreads();
  if (ex >= 0) {
    int rank = __popcll(myBal & ((1ull << lane) - 1ull));
    perm[bb[ex] + wo[w][ex] + rank] = e;
  }
}

// ======== GEMM: BM=64, A in LDS (4 blocks/CU), LDS-transpose epilogue ========
// FIXB: counts come from scatter cursors, bucket base = ex*E_TOT (3-node path).
template <bool PRE, bool FIXB>
__launch_bounds__(256, 4)
__global__ void gemm_kernel(const float* __restrict__ x, const float* __restrict__ W,
                            const unsigned short* __restrict__ Wbf,
                            const float* __restrict__ bias, const int* __restrict__ index,
                            const int* __restrict__ cnts, const int* __restrict__ perm,
                            float* __restrict__ out) {
  __shared__ __align__(16) unsigned short lA[BM * LDK];   // 33.75 KB, reused as f32 scratch
  __shared__ int srcRow[BM];
  __shared__ int outRow[BM];

  // block -> (expert, row-tile)
  int t = (int)blockIdx.x;
  int ex = -1, trow = 0, cnt = 0, accT = 0, base = 0, run = 0;
#pragma unroll
  for (int i = 0; i < N_EXP; ++i) {
    int c = cnts[i];
    int nt = (c + BM - 1) / BM;
    if (ex < 0 && t < accT + nt) { ex = i; trow = t - accT; cnt = c; base = run; }
    accT += nt;
    run += c;
  }
  if (ex < 0) return;
  int row0 = (FIXB ? ex * E_TOT : base) + trow * BM;
  int rows = min(BM, cnt - trow * BM);

  const int tt = threadIdx.x;
  if (tt < BM) {
    int rr = min(tt, rows - 1);       // tail: duplicate last valid row, masked at store
    int e = perm[row0 + rr];
    outRow[tt] = e;
    srcRow[tt] = index[e];
  }
  __syncthreads();

  // stage A: gather 64 rows x 256 f32 -> bf16 LDS (1KB coalesced per row)
#pragma unroll
  for (int i = 0; i < 16; ++i) {
    int lin = i * 256 + tt;
    int rr = lin >> 6;
    int c4 = lin & 63;
    const float4 v = ((const float4*)(x + (size_t)srcRow[rr] * D_DIM))[c4];
    ushort4 o4;
    o4.x = f2bf(v.x); o4.y = f2bf(v.y); o4.z = f2bf(v.z); o4.w = f2bf(v.w);
    *(ushort4*)&lA[rr * LDK + c4 * 4] = o4;
  }
  __syncthreads();

  const int w = tt >> 6, lane = tt & 63, quad = lane >> 4, l16 = lane & 15;

  // K-loop: wave w owns cols [w*64, w*64+64)
  f32x4 acc[4][4];
#pragma unroll
  for (int mt = 0; mt < 4; ++mt)
#pragma unroll
    for (int nt = 0; nt < 4; ++nt) acc[mt][nt] = (f32x4){0.f, 0.f, 0.f, 0.f};

#pragma unroll
  for (int ks = 0; ks < 8; ++ks) {
    int k0 = ks * 32 + quad * 8;
    bf16x8 a[4], b[4];
#pragma unroll
    for (int mt = 0; mt < 4; ++mt)
      a[mt] = *(const bf16x8*)&lA[(mt * 16 + l16) * LDK + k0];
#pragma unroll
    for (int nt = 0; nt < 4; ++nt) {
      int col = w * 64 + nt * 16 + l16;   // W row (output col)
      if (PRE) {
        b[nt] = *(const bf16x8*)&Wbf[((size_t)ex * D_DIM + col) * D_DIM + k0];
      } else {
        const float* wp = W + ((size_t)ex * D_DIM + col) * D_DIM + k0;
        float4 v0 = ((const float4*)wp)[0];
        float4 v1 = ((const float4*)wp)[1];
        bf16x8 bb;
        bb[0] = (short)f2bf(v0.x); bb[1] = (short)f2bf(v0.y);
        bb[2] = (short)f2bf(v0.z); bb[3] = (short)f2bf(v0.w);
        bb[4] = (short)f2bf(v1.x); bb[5] = (short)f2bf(v1.y);
        bb[6] = (short)f2bf(v1.z); bb[7] = (short)f2bf(v1.w);
        b[nt] = bb;
      }
    }
#pragma unroll
    for (int mt = 0; mt < 4; ++mt)
#pragma unroll
      for (int nt = 0; nt < 4; ++nt)
        acc[mt][nt] = __builtin_amdgcn_mfma_f32_16x16x32_bf16(a[mt], b[nt], acc[mt][nt], 0, 0, 0);
  }

  // bias (reused across both chunks)
  float bv[4];
#pragma unroll
  for (int nt = 0; nt < 4; ++nt) bv[nt] = bias[ex * D_DIM + w * 64 + nt * 16 + l16];

  // epilogue: transpose 32-row chunks through LDS -> contiguous 128B nontemporal row stores
  float* lsf = (float*)lA;   // 32 x LDF f32 scratch (33280B <= 33792B)
#pragma unroll
  for (int chunk = 0; chunk < 2; ++chunk) {
    __syncthreads();   // lA/lsf reads (K-loop / prev chunk) complete before overwrite
#pragma unroll
    for (int mtl = 0; mtl < 2; ++mtl) {
      int mt = chunk * 2 + mtl;
#pragma unroll
      for (int nt = 0; nt < 4; ++nt) {
        int col = w * 64 + nt * 16 + l16;
#pragma unroll
        for (int r = 0; r < 4; ++r) {
          int lr = mtl * 16 + quad * 4 + r;           // chunk-local row 0..31
          lsf[lr * LDF + col] = acc[mt][nt][r] + bv[nt];
        }
      }
    }
    __syncthreads();
    int r8 = tt >> 3, c8 = tt & 7;
    int grow = chunk * 32 + r8;
    if (grow < rows) {
      float* op = out + (size_t)outRow[grow] * D_DIM;
#pragma unroll
      for (int j = 0; j < 8; ++j) {
        int c4 = c8 + j * 8;                           // 8 lanes -> 128B contiguous per row
        f32x4 v4 = *(const f32x4*)&lsf[r8 * LDF + c4 * 4];
        __builtin_nontemporal_store(v4, (f32x4*)(op + c4 * 4));
      }
    }
  }
}

extern "C" void kernel_launch(void* const* d_in, const int* in_sizes, int n_in,
                              void* d_out, int out_size, void* d_ws, size_t ws_size,
                              hipStream_t stream) {
  const float* x     = (const float*)d_in[0];
  const float* W     = (const float*)d_in[1];
  const float* bias  = (const float*)d_in[2];
  const int*   index = (const int*)d_in[3];
  const void*  masks = d_in[4];
  float* out = (float*)d_out;

  int* hdr = (int*)d_ws;               // [0..4] counts, [6] is_u8, [16..20] cursors
  const size_t wbfB  = (size_t)N_EXP * D_DIM * D_DIM * 2;  // 655360
  const size_t permB = (size_t)E_TOT * 4;                  // 1.2 MB
  const bool fix3 = (ws_size >= 1024 + wbfB + (size_t)N_EXP * permB);  // 6MB perm
  const bool pre  = fix3 || (ws_size >= 1024 + wbfB + permB);
  size_t off = 1024;
  unsigned short* Wbf = nullptr;
  if (pre) { Wbf = (unsigned short*)((char*)d_ws + off); off += wbfB; }
  int* perm = (int*)((char*)d_ws + off);

  (void)hipMemsetAsync(d_ws, 0, 1024, stream);   // zero counts + cursors each replay

  if (fix3) {
    // 3-node path: memset -> scatter_conv -> gemm
    scatter_conv_kernel<<<NB_CNT, 256, 0, stream>>>(W, Wbf, masks, hdr + 16, perm, 1);
    gemm_kernel<true, true><<<MAX_TILES, 256, 0, stream>>>(x, W, Wbf, bias, index,
                                                           hdr + 16, perm, out);
  } else {
    prep_kernel<<<NB_CNT, 256, 0, stream>>>(W, Wbf, masks, hdr, pre ? 1 : 0);
    scatter_kernel<<<NB_CNT, 256, 0, stream>>>(masks, hdr, hdr + 16, perm);
    if (pre)
      gemm_kernel<true, false><<<MAX_TILES, 256, 0, stream>>>(x, W, Wbf, bias, index,
                                                              hdr, perm, out);
    else
      gemm_kernel<false, false><<<MAX_TILES, 256, 0, stream>>>(x, W, Wbf, bias, index,
                                                               hdr, perm, out);
  }
}

// Round 7
// 450.167 us; speedup vs baseline: 1.2183x; 1.0293x over previous
//
#include <hip/hip_runtime.h>

#define E_TOT   300000
#define D_DIM   256
#define N_EXP   5
#define BM      64
#define LDK     264           // bf16 A-tile stride for FALLBACK staging (256 + 8 pad)
#define LDF     260           // f32 epilogue scratch stride (2-way alias = free)
#define NB_CNT  ((E_TOT + 255) / 256)          // 1172
#define MAX_TILES (E_TOT / BM + N_EXP)         // 4697

typedef __attribute__((ext_vector_type(8))) short bf16x8;
typedef __attribute__((ext_vector_type(4))) float f32x4;

__device__ inline unsigned short f2bf(float f) {
  union { float f; unsigned u; } v; v.f = f;
  unsigned u = v.u;
  u += 0x7FFFu + ((u >> 16) & 1u);   // round-to-nearest-even
  return (unsigned short)(u >> 16);
}

__device__ inline int get_expert(const void* masks, int e, bool is_u8) {
  if (is_u8) {
    const unsigned char* m = (const unsigned char*)masks;
#pragma unroll
    for (int i = 0; i < N_EXP; ++i) if (m[(size_t)i * E_TOT + e]) return i;
  } else {
    const int* m = (const int*)masks;
#pragma unroll
    for (int i = 0; i < N_EXP; ++i) if (m[(size_t)i * E_TOT + e]) return i;
  }
  return 0;
}

// ======== node 2: single-pass scatter into FIXED expert regions + W/x -> bf16 ========
// Fixed bases (ex*E_TOT) need no count pass; blocks reserve ranges via 5 atomic
// cursors; gemm reads finalized cursors as counts. u8-vs-i32 self-detect per block
// (one-hot per slot <=> exactly one true byte; i32-as-u8 gives cnt==0 slots in every
// block). W and x converted to bf16 here so gemm can use global_load_lds staging.
__global__ void scatter_conv_kernel(const float* __restrict__ W,
                                    unsigned short* __restrict__ Wbf,
                                    const float* __restrict__ x,
                                    unsigned short* __restrict__ xbf, int nx4,
                                    const void* __restrict__ masks,
                                    int* __restrict__ cursor, int* __restrict__ perm,
                                    int doConv, int doXconv) {
  __shared__ int wc[4][N_EXP];
  __shared__ int wo[4][N_EXP];
  __shared__ int bb[N_EXP];
  __shared__ int s_u8ok;
  const int tt = threadIdx.x, w = tt >> 6, lane = tt & 63;
  const int e = (int)blockIdx.x * 256 + tt;
  const int gsz = (int)gridDim.x * 256;

  const unsigned char* m8 = (const unsigned char*)masks;
  int cnt1 = 1, ex = -1;
  if (e < E_TOT) {
    cnt1 = 0; int exu = 0;
#pragma unroll
    for (int i = 0; i < N_EXP; ++i) {
      int tb = (m8[(size_t)i * E_TOT + e] != 0);
      cnt1 += tb; if (tb) exu = i;
    }
    ex = exu;
  }
  if (tt == 0) s_u8ok = 1;
  __syncthreads();
  if (cnt1 != 1) s_u8ok = 0;         // benign all-write-0 race
  __syncthreads();
  if (!s_u8ok && e < E_TOT) ex = get_expert(masks, e, false);

  unsigned long long myBal = 0;
#pragma unroll
  for (int i = 0; i < N_EXP; ++i) {
    unsigned long long bal = __ballot(ex == i);
    if (lane == 0) wc[w][i] = __popcll(bal);
    if (ex == i) myBal = bal;
  }
  // bf16 conversions ride in this dispatch (pure BW, overlaps the ballot/scan sync)
  if (doConv) {
    const int n4 = (N_EXP * D_DIM * D_DIM) / 4;   // 81920 float4s
    for (int i = e; i < n4; i += gsz) {
      float4 v = ((const float4*)W)[i];
      ushort4 o4;
      o4.x = f2bf(v.x); o4.y = f2bf(v.y); o4.z = f2bf(v.z); o4.w = f2bf(v.w);
      ((ushort4*)Wbf)[i] = o4;
    }
  }
  if (doXconv) {
    for (int i = e; i < nx4; i += gsz) {
      float4 v = ((const float4*)x)[i];
      ushort4 o4;
      o4.x = f2bf(v.x); o4.y = f2bf(v.y); o4.z = f2bf(v.z); o4.w = f2bf(v.w);
      ((ushort4*)xbf)[i] = o4;
    }
  }
  __syncthreads();
  if (tt < 4 * N_EXP) {
    int ww = tt / N_EXP, ii = tt % N_EXP;
    int s = 0;
    for (int p = 0; p < ww; ++p) s += wc[p][ii];
    wo[ww][ii] = s;
  }
  if (tt < N_EXP) {
    int tot = wc[0][tt] + wc[1][tt] + wc[2][tt] + wc[3][tt];
    int old = atomicAdd(&cursor[tt], tot);
    bb[tt] = tt * E_TOT + old;        // fixed expert region base
  }
  __syncthreads();
  if (ex >= 0) {
    int rank = __popcll(myBal & ((1ull << lane) - 1ull));
    perm[bb[ex] + wo[w][ex] + rank] = e;
  }
}

// ======== node 3: GEMM ========
// XPRE: A staged via global_load_lds(16B) from pre-converted xbf. LDS is linear
// [64][512B]; bank behavior preserved by XOR swizzle byte^=((row&7)<<4) applied to
// the per-lane GLOBAL source address (m173 pattern) and to the ds_read address.
// Else: legacy f32->reg->cvt->ds_write staging with LDK pad.
template <bool PRE, bool FIXB, bool XPRE>
__launch_bounds__(256, 4)
__global__ void gemm_kernel(const float* __restrict__ x, const float* __restrict__ W,
                            const unsigned short* __restrict__ Wbf,
                            const unsigned short* __restrict__ xbf,
                            const float* __restrict__ bias, const int* __restrict__ index,
                            const int* __restrict__ cnts, const int* __restrict__ perm,
                            float* __restrict__ out) {
  __shared__ __align__(16) unsigned short lA[BM * LDK];   // 33.75 KB, reused as f32 scratch
  __shared__ int srcRow[BM];
  __shared__ int outRow[BM];

  // block -> (expert, row-tile)
  int t = (int)blockIdx.x;
  int ex = -1, trow = 0, cnt = 0, accT = 0, base = 0, run = 0;
#pragma unroll
  for (int i = 0; i < N_EXP; ++i) {
    int c = cnts[i];
    int nt = (c + BM - 1) / BM;
    if (ex < 0 && t < accT + nt) { ex = i; trow = t - accT; cnt = c; base = run; }
    accT += nt;
    run += c;
  }
  if (ex < 0) return;
  int row0 = (FIXB ? ex * E_TOT : base) + trow * BM;
  int rows = min(BM, cnt - trow * BM);

  const int tt = threadIdx.x;
  const int w = tt >> 6, lane = tt & 63, quad = lane >> 4, l16 = lane & 15;

  if (tt < BM) {
    int rr = min(tt, rows - 1);       // tail: duplicate last valid row, masked at store
    int e = perm[row0 + rr];
    outRow[tt] = e;
    srcRow[tt] = index[e];
  }
  __syncthreads();

  if (XPRE) {
    // async DMA: 8 x 1KB per wave (2 rows each), linear LDS dest, swizzled source
    char* lab = (char*)lA;
#pragma unroll
    for (int i = 0; i < 8; ++i) {
      int r0 = (w << 4) + i * 2;
      int r = r0 + (lane >> 5);
      int q = ((lane & 31) * 16) ^ ((r & 7) << 4);
      const char* gp = (const char*)(xbf + (size_t)srcRow[r] * D_DIM) + q;
      __builtin_amdgcn_global_load_lds(
          (const __attribute__((address_space(1))) void*)gp,
          (__attribute__((address_space(3))) void*)(lab + r0 * 512),
          16, 0, 0);
    }
  } else {
    // legacy: gather 64 rows x 256 f32 -> bf16 LDS (1KB coalesced per row)
#pragma unroll
    for (int i = 0; i < 16; ++i) {
      int lin = i * 256 + tt;
      int rr = lin >> 6;
      int c4 = lin & 63;
      const float4 v = ((const float4*)(x + (size_t)srcRow[rr] * D_DIM))[c4];
      ushort4 o4;
      o4.x = f2bf(v.x); o4.y = f2bf(v.y); o4.z = f2bf(v.z); o4.w = f2bf(v.w);
      *(ushort4*)&lA[rr * LDK + c4 * 4] = o4;
    }
  }
  __syncthreads();   // compiler drains vmcnt(0) before barrier -> DMA complete

  // K-loop: wave w owns cols [w*64, w*64+64)
  f32x4 acc[4][4];
#pragma unroll
  for (int mt = 0; mt < 4; ++mt)
#pragma unroll
    for (int nt = 0; nt < 4; ++nt) acc[mt][nt] = (f32x4){0.f, 0.f, 0.f, 0.f};

  const char* labr = (const char*)lA;
#pragma unroll
  for (int ks = 0; ks < 8; ++ks) {
    int k0 = ks * 32 + quad * 8;
    bf16x8 a[4], b[4];
#pragma unroll
    for (int mt = 0; mt < 4; ++mt) {
      int r = mt * 16 + l16;
      if (XPRE)
        a[mt] = *(const bf16x8*)(labr + r * 512 + ((k0 * 2) ^ ((l16 & 7) << 4)));
      else
        a[mt] = *(const bf16x8*)&lA[r * LDK + k0];
    }
#pragma unroll
    for (int nt = 0; nt < 4; ++nt) {
      int col = w * 64 + nt * 16 + l16;   // W row (output col)
      if (PRE) {
        b[nt] = *(const bf16x8*)&Wbf[((size_t)ex * D_DIM + col) * D_DIM + k0];
      } else {
        const float* wp = W + ((size_t)ex * D_DIM + col) * D_DIM + k0;
        float4 v0 = ((const float4*)wp)[0];
        float4 v1 = ((const float4*)wp)[1];
        bf16x8 bb;
        bb[0] = (short)f2bf(v0.x); bb[1] = (short)f2bf(v0.y);
        bb[2] = (short)f2bf(v0.z); bb[3] = (short)f2bf(v0.w);
        bb[4] = (short)f2bf(v1.x); bb[5] = (short)f2bf(v1.y);
        bb[6] = (short)f2bf(v1.z); bb[7] = (short)f2bf(v1.w);
        b[nt] = bb;
      }
    }
#pragma unroll
    for (int mt = 0; mt < 4; ++mt)
#pragma unroll
      for (int nt = 0; nt < 4; ++nt)
        acc[mt][nt] = __builtin_amdgcn_mfma_f32_16x16x32_bf16(a[mt], b[nt], acc[mt][nt], 0, 0, 0);
  }

  // bias (reused across chunks)
  float bv[4];
#pragma unroll
  for (int nt = 0; nt < 4; ++nt) bv[nt] = bias[ex * D_DIM + w * 64 + nt * 16 + l16];

  // epilogue: 4 x 16-row chunks through LDS -> contiguous 256B nontemporal row stores
  float* lsf = (float*)lA;   // 16 x LDF f32 scratch (16.6 KB <= 33.75 KB)
#pragma unroll
  for (int mt = 0; mt < 4; ++mt) {
    __syncthreads();   // lA/lsf reads (K-loop / prev chunk) complete before overwrite
#pragma unroll
    for (int nt = 0; nt < 4; ++nt) {
      int col = w * 64 + nt * 16 + l16;
#pragma unroll
      for (int r = 0; r < 4; ++r) {
        int lr = quad * 4 + r;                        // chunk-local row 0..15
        lsf[lr * LDF + col] = acc[mt][nt][r] + bv[nt];
      }
    }
    __syncthreads();
    int r16 = tt >> 4, c16 = tt & 15;
    int grow = mt * 16 + r16;
    if (grow < rows) {
      float* op = out + (size_t)outRow[grow] * D_DIM;
#pragma unroll
      for (int j = 0; j < 4; ++j) {
        int c4 = c16 + j * 16;                        // 16 lanes -> 256B contiguous
        f32x4 v4 = *(const f32x4*)&lsf[r16 * LDF + c4 * 4];
        __builtin_nontemporal_store(v4, (f32x4*)(op + c4 * 4));
      }
    }
  }
}

// ======== fallback (small ws): 4-node prep+scatter, compact perm ========
__global__ void prep_kernel(const float* __restrict__ W, unsigned short* __restrict__ Wbf,
                            const void* __restrict__ masks, int* __restrict__ hdr,
                            int doConv) {
  __shared__ int wc[4][N_EXP];
  __shared__ int s_u8ok;
  const int tt = threadIdx.x, w = tt >> 6, lane = tt & 63;
  const int gtid = (int)blockIdx.x * 256 + tt;

  const unsigned char* m8 = (const unsigned char*)masks;
  int cnt1 = 1, ex = -1;
  if (gtid < E_TOT) {
    cnt1 = 0; int exu = 0;
#pragma unroll
    for (int i = 0; i < N_EXP; ++i) {
      int tb = (m8[(size_t)i * E_TOT + gtid] != 0);
      cnt1 += tb; if (tb) exu = i;
    }
    ex = exu;
  }
  if (tt == 0) s_u8ok = 1;
  __syncthreads();
  if (cnt1 != 1) s_u8ok = 0;
  __syncthreads();
  const int is_u8 = s_u8ok;
  if (!is_u8 && gtid < E_TOT) ex = get_expert(masks, gtid, false);

#pragma unroll
  for (int i = 0; i < N_EXP; ++i) {
    unsigned long long bal = __ballot(ex == i);
    if (lane == 0) wc[w][i] = __popcll(bal);
  }
  if (doConv) {
    const int n4 = (N_EXP * D_DIM * D_DIM) / 4;
    for (int i = gtid; i < n4; i += (int)gridDim.x * 256) {
      float4 v = ((const float4*)W)[i];
      ushort4 o4;
      o4.x = f2bf(v.x); o4.y = f2bf(v.y); o4.z = f2bf(v.z); o4.w = f2bf(v.w);
      ((ushort4*)Wbf)[i] = o4;
    }
  }
  __syncthreads();
  if (tt < N_EXP)
    atomicAdd(&hdr[tt], wc[0][tt] + wc[1][tt] + wc[2][tt] + wc[3][tt]);
  if (tt == 0 && blockIdx.x == 0) hdr[6] = is_u8;
}

__global__ void scatter_kernel(const void* __restrict__ masks, const int* __restrict__ hdr,
                               int* __restrict__ cursor, int* __restrict__ perm) {
  __shared__ int wc[4][N_EXP];
  __shared__ int wo[4][N_EXP];
  __shared__ int bb[N_EXP];
  const int tt = threadIdx.x, w = tt >> 6, lane = tt & 63;
  const int e = (int)blockIdx.x * 256 + tt;
  const bool is_u8 = (hdr[6] != 0);

  int ex = (e < E_TOT) ? get_expert(masks, e, is_u8) : -1;
  unsigned long long myBal = 0;
#pragma unroll
  for (int i = 0; i < N_EXP; ++i) {
    unsigned long long bal = __ballot(ex == i);
    if (lane == 0) wc[w][i] = __popcll(bal);
    if (ex == i) myBal = bal;
  }
  __syncthreads();
  if (tt < 4 * N_EXP) {
    int ww = tt / N_EXP, ii = tt % N_EXP;
    int s = 0;
    for (int p = 0; p < ww; ++p) s += wc[p][ii];
    wo[ww][ii] = s;
  }
  if (tt < N_EXP) {
    int tot = wc[0][tt] + wc[1][tt] + wc[2][tt] + wc[3][tt];
    int old = atomicAdd(&cursor[tt], tot);
    int base = 0;
    for (int i = 0; i < tt; ++i) base += hdr[i];
    bb[tt] = base + old;
  }
  __syncthreads();
  if (ex >= 0) {
    int rank = __popcll(myBal & ((1ull << lane) - 1ull));
    perm[bb[ex] + wo[w][ex] + rank] = e;
  }
}

extern "C" void kernel_launch(void* const* d_in, const int* in_sizes, int n_in,
                              void* d_out, int out_size, void* d_ws, size_t ws_size,
                              hipStream_t stream) {
  const float* x     = (const float*)d_in[0];
  const float* W     = (const float*)d_in[1];
  const float* bias  = (const float*)d_in[2];
  const int*   index = (const int*)d_in[3];
  const void*  masks = d_in[4];
  float* out = (float*)d_out;

  int* hdr = (int*)d_ws;               // [0..4] counts, [6] is_u8, [16..20] cursors
  const size_t wbfB  = (size_t)N_EXP * D_DIM * D_DIM * 2;  // 655360
  const size_t permB = (size_t)E_TOT * 4;                  // 1.2 MB
  const size_t xbfB  = (size_t)in_sizes[0] * 2;            // 51.2 MB (bf16 x)
  const int    nx4   = in_sizes[0] / 4;

  const bool xpre = (ws_size >= 1024 + wbfB + (size_t)N_EXP * permB + xbfB);
  const bool fix3 = xpre || (ws_size >= 1024 + wbfB + (size_t)N_EXP * permB);
  const bool pre  = fix3 || (ws_size >= 1024 + wbfB + permB);
  size_t off = 1024;
  unsigned short* Wbf = nullptr;
  if (pre) { Wbf = (unsigned short*)((char*)d_ws + off); off += wbfB; }
  int* perm = (int*)((char*)d_ws + off); off += (fix3 ? (size_t)N_EXP * permB : permB);
  unsigned short* xbf = (unsigned short*)((char*)d_ws + off);

  (void)hipMemsetAsync(d_ws, 0, 1024, stream);   // zero counts + cursors each replay

  if (fix3) {
    scatter_conv_kernel<<<NB_CNT, 256, 0, stream>>>(W, Wbf, x, xbf, nx4, masks,
                                                    hdr + 16, perm, 1, xpre ? 1 : 0);
    if (xpre)
      gemm_kernel<true, true, true><<<MAX_TILES, 256, 0, stream>>>(
          x, W, Wbf, xbf, bias, index, hdr + 16, perm, out);
    else
      gemm_kernel<true, true, false><<<MAX_TILES, 256, 0, stream>>>(
          x, W, Wbf, xbf, bias, index, hdr + 16, perm, out);
  } else {
    prep_kernel<<<NB_CNT, 256, 0, stream>>>(W, Wbf, masks, hdr, pre ? 1 : 0);
    scatter_kernel<<<NB_CNT, 256, 0, stream>>>(masks, hdr, hdr + 16, perm);
    if (pre)
      gemm_kernel<true, false, false><<<MAX_TILES, 256, 0, stream>>>(
          x, W, Wbf, xbf, bias, index, hdr, perm, out);
    else
      gemm_kernel<false, false, false><<<MAX_TILES, 256, 0, stream>>>(
          x, W, Wbf, xbf, bias, index, hdr, perm, out);
  }
}